// Round 1
// baseline (44149.115 us; speedup 1.0000x reference)
//
#include <hip/hip_runtime.h>

// ---------------------------------------------------------------------------
// 2-layer LSTM (S=4096, B=64, I=14, H=256) + ReLU + FC(256->1), eval mode.
// Persistent 3-stage pipelined scan: 12 workgroups total.
//   stage0 (blocks 0-3):  layer0 scan, 16 chains/WG, K=288 (h256|x14|pad18)
//   stageP (blocks 4-7):  pre1[s] = W_ih1 @ h0[s] + b1   (feed-forward)
//   stage1 (blocks 8-11): layer1 scan, K=256, acc init from pre1, fused FC
// f16 MFMA (16x16x32), fp32 accumulate + fp32 cell state + fp32 gates math.
// ---------------------------------------------------------------------------

#define S_LEN 4096
#define BATCH 64
#define IN_DIM 14
#define HID 256
#define GATES 1024
#define K0 288      // layer0 K (padded)
#define LDA0 296    // LDS A row stride (f16), stage0: (296*2/4)%32=20 -> 2-way only
#define K1 256
#define LDA1 264    // (264*2/4)%32=4 -> 2-way only

typedef _Float16 half8 __attribute__((ext_vector_type(8)));
typedef float f32x4 __attribute__((ext_vector_type(4)));

__device__ __forceinline__ float sigf(float z) { return 1.0f / (1.0f + __expf(-z)); }
__device__ __forceinline__ float tanhf2(float z) { return 2.0f / (1.0f + __expf(-2.0f * z)) - 1.0f; }

__device__ __forceinline__ void wait_ge(int* p, int v) {
    while (__hip_atomic_load(p, __ATOMIC_ACQUIRE, __HIP_MEMORY_SCOPE_AGENT) < v)
        __builtin_amdgcn_s_sleep(2);
}
__device__ __forceinline__ void set_flag(int* p, int v) {
    __hip_atomic_store(p, v, __ATOMIC_RELEASE, __HIP_MEMORY_SCOPE_AGENT);
}

// ---------------------------------------------------------------------------
__global__ void prep_weights(const float* __restrict__ Wih0, const float* __restrict__ Whh0,
                             const float* __restrict__ bih0, const float* __restrict__ bhh0,
                             const float* __restrict__ Wih1, const float* __restrict__ Whh1,
                             const float* __restrict__ bih1, const float* __restrict__ bhh1,
                             _Float16* __restrict__ wcat0, _Float16* __restrict__ wih1h,
                             _Float16* __restrict__ whh1h, float* __restrict__ b0,
                             float* __restrict__ b1) {
    int idx0 = blockIdx.x * blockDim.x + threadIdx.x;
    int stride = gridDim.x * blockDim.x;
    for (int i = idx0; i < GATES * K0; i += stride) {
        int n = i / K0, k = i % K0;
        float v = 0.f;
        if (k < HID) v = Whh0[n * HID + k];
        else if (k < HID + IN_DIM) v = Wih0[n * IN_DIM + (k - HID)];
        wcat0[i] = (_Float16)v;
    }
    for (int i = idx0; i < GATES * HID; i += stride) {
        wih1h[i] = (_Float16)Wih1[i];
        whh1h[i] = (_Float16)Whh1[i];
    }
    for (int i = idx0; i < GATES; i += stride) {
        b0[i] = bih0[i] + bhh0[i];
        b1[i] = bih1[i] + bhh1[i];
    }
}

// ---------------------------------------------------------------------------
__global__ __launch_bounds__(512, 2) void lstm_scan(
    const float* __restrict__ x, const float* __restrict__ h0, const float* __restrict__ c0,
    const _Float16* __restrict__ wcat0, const _Float16* __restrict__ wih1,
    const _Float16* __restrict__ whh1, const float* __restrict__ b0,
    const float* __restrict__ b1, const float* __restrict__ wfc,
    const float* __restrict__ bfc, _Float16* __restrict__ hs0ring,
    float* __restrict__ pre1ring, int* __restrict__ flags, float* __restrict__ out,
    int R0, int R1) {
    const int stage = blockIdx.x >> 2;
    const int g = blockIdx.x & 3;
    const int tid = threadIdx.x;
    const int w = tid >> 6;          // wave 0..7
    const int lane = tid & 63;
    const int quad = lane >> 4;      // 0..3
    const int col = lane & 15;       // 0..15
    const int c0b = g * 16;          // chain base (global batch index)

    int* flag0  = flags + g * 64;          // stage0 produced h0[s]
    int* flagPc = flags + 1024 + g * 64;   // stageP consumed hs0[s]
    int* flagPd = flags + 2048 + g * 64;   // stageP produced pre1[s]
    int* flag1c = flags + 3072 + g * 64;   // stage1 consumed pre1[s]

    __shared__ __align__(16) _Float16 Ash[16 * LDA0];
    __shared__ float red[8][16];

    if (stage == 0) {
        // ---------------- layer0 scan ----------------
        // init A: h0[layer0] -> cols [0,256); zero pad cols [270,288)
        {
            int m = tid >> 5, cw = tid & 31;
            const float* hp = h0 + (0 * BATCH + c0b + m) * HID + cw * 8;
            half8 hv;
#pragma unroll
            for (int j = 0; j < 8; ++j) hv[j] = (_Float16)hp[j];
            *(half8*)&Ash[m * LDA0 + cw * 8] = hv;
            if (cw >= IN_DIM) Ash[m * LDA0 + HID + cw] = (_Float16)0.f;
        }
        if (tid < 16 * IN_DIM) {
            int m = tid / IN_DIM, d = tid % IN_DIM;
            Ash[m * LDA0 + HID + d] = (_Float16)x[(0 * BATCH + c0b + m) * IN_DIM + d];
        }
        float bs[8];
#pragma unroll
        for (int a = 0; a < 8; ++a) bs[a] = b0[(w + 8 * a) * 16 + col];
        float cst[8];
#pragma unroll
        for (int a2 = 0; a2 < 2; ++a2)
#pragma unroll
            for (int r = 0; r < 4; ++r)
                cst[a2 * 4 + r] = c0[(0 * BATCH + c0b + quad * 4 + r) * HID + (w + 8 * a2) * 16 + col];
        const _Float16* wb = wcat0 + (w * 16 + col) * K0 + quad * 8;
        __syncthreads();

        for (int s = 0; s < S_LEN; ++s) {
            f32x4 acc[8];
#pragma unroll
            for (int a = 0; a < 8; ++a) acc[a] = (f32x4){bs[a], bs[a], bs[a], bs[a]};
            for (int kk = 0; kk < K0 / 32; ++kk) {
                half8 av = *(const half8*)&Ash[col * LDA0 + kk * 32 + quad * 8];
#pragma unroll
                for (int a = 0; a < 8; ++a) {
                    half8 bv = *(const half8*)(wb + a * (128 * K0) + kk * 32);
                    acc[a] = __builtin_amdgcn_mfma_f32_16x16x32_f16(av, bv, acc[a], 0, 0, 0);
                }
            }
            if (tid == 0 && s >= R0) wait_ge(flagPc, s - R0 + 1);  // ring guard
            __syncthreads();  // all A reads done; safe to overwrite

            int slot = s & (R0 - 1);
#pragma unroll
            for (int a2 = 0; a2 < 2; ++a2) {
                int j = (w + 8 * a2) * 16 + col;
#pragma unroll
                for (int r = 0; r < 4; ++r) {
                    int m = quad * 4 + r;
                    float iv = sigf(acc[0 + a2][r]);
                    float fv = sigf(acc[2 + a2][r]);
                    float gv = tanhf2(acc[4 + a2][r]);
                    float ov = sigf(acc[6 + a2][r]);
                    float c = fv * cst[a2 * 4 + r] + iv * gv;
                    cst[a2 * 4 + r] = c;
                    float hv = ov * tanhf2(c);
                    _Float16 hh = (_Float16)hv;
                    Ash[m * LDA0 + j] = hh;
                    hs0ring[(size_t)slot * (BATCH * HID) + (c0b + m) * HID + j] = hh;
                }
            }
            if (s + 1 < S_LEN && tid < 16 * IN_DIM) {
                int m = tid / IN_DIM, d = tid % IN_DIM;
                Ash[m * LDA0 + HID + d] = (_Float16)x[((s + 1) * BATCH + c0b + m) * IN_DIM + d];
            }
            __syncthreads();
            if (tid == 0) { __threadfence(); set_flag(flag0, s + 1); }
        }
    } else if (stage == 1) {
        // ---------------- pre1 = W_ih1 @ h0[s] + b1 ----------------
        float bs[8];
#pragma unroll
        for (int a = 0; a < 8; ++a) bs[a] = b1[(w + 8 * a) * 16 + col];
        const _Float16* wb = wih1 + (w * 16 + col) * K1 + quad * 8;

        for (int s = 0; s < S_LEN; ++s) {
            if (tid == 0) {
                wait_ge(flag0, s + 1);
                if (s >= R1) wait_ge(flag1c, s - R1 + 1);  // pre1 ring guard
            }
            __syncthreads();
            {
                int m = tid >> 5, cw = tid & 31;
                half8 v = *(const half8*)&hs0ring[(size_t)(s & (R0 - 1)) * (BATCH * HID) +
                                                  (c0b + m) * HID + cw * 8];
                *(half8*)&Ash[m * LDA1 + cw * 8] = v;
            }
            __syncthreads();
            if (tid == 0) set_flag(flagPc, s + 1);  // done reading hs0[s]

            f32x4 acc[8];
#pragma unroll
            for (int a = 0; a < 8; ++a) acc[a] = (f32x4){bs[a], bs[a], bs[a], bs[a]};
            for (int kk = 0; kk < K1 / 32; ++kk) {
                half8 av = *(const half8*)&Ash[col * LDA1 + kk * 32 + quad * 8];
#pragma unroll
                for (int a = 0; a < 8; ++a) {
                    half8 bv = *(const half8*)(wb + a * (128 * K1) + kk * 32);
                    acc[a] = __builtin_amdgcn_mfma_f32_16x16x32_f16(av, bv, acc[a], 0, 0, 0);
                }
            }
            float* pp = pre1ring + ((size_t)g * R1 + (s & (R1 - 1))) * (16 * GATES);
#pragma unroll
            for (int a = 0; a < 8; ++a) {
                int n = (w + 8 * a) * 16 + col;
#pragma unroll
                for (int r = 0; r < 4; ++r) pp[(quad * 4 + r) * GATES + n] = acc[a][r];
            }
            __syncthreads();
            if (tid == 0) { __threadfence(); set_flag(flagPd, s + 1); }
        }
    } else {
        // ---------------- layer1 scan + fused ReLU/FC ----------------
        {
            int m = tid >> 5, cw = tid & 31;
            const float* hp = h0 + (1 * BATCH + c0b + m) * HID + cw * 8;
            half8 hv;
#pragma unroll
            for (int j = 0; j < 8; ++j) hv[j] = (_Float16)hp[j];
            *(half8*)&Ash[m * LDA1 + cw * 8] = hv;
        }
        float cst[8], wf[2];
#pragma unroll
        for (int a2 = 0; a2 < 2; ++a2) {
            wf[a2] = wfc[(w + 8 * a2) * 16 + col];
#pragma unroll
            for (int r = 0; r < 4; ++r)
                cst[a2 * 4 + r] = c0[(1 * BATCH + c0b + quad * 4 + r) * HID + (w + 8 * a2) * 16 + col];
        }
        const float bfcv = bfc[0];
        const _Float16* wb = whh1 + (w * 16 + col) * K1 + quad * 8;
        __syncthreads();

        for (int s = 0; s < S_LEN; ++s) {
            if (tid == 0) wait_ge(flagPd, s + 1);
            __syncthreads();
            const float* pp = pre1ring + ((size_t)g * R1 + (s & (R1 - 1))) * (16 * GATES);
            f32x4 acc[8];
#pragma unroll
            for (int a = 0; a < 8; ++a) {
                int n = (w + 8 * a) * 16 + col;
#pragma unroll
                for (int r = 0; r < 4; ++r) acc[a][r] = pp[(quad * 4 + r) * GATES + n];
            }
            for (int kk = 0; kk < K1 / 32; ++kk) {
                half8 av = *(const half8*)&Ash[col * LDA1 + kk * 32 + quad * 8];
#pragma unroll
                for (int a = 0; a < 8; ++a) {
                    half8 bv = *(const half8*)(wb + a * (128 * K1) + kk * 32);
                    acc[a] = __builtin_amdgcn_mfma_f32_16x16x32_f16(av, bv, acc[a], 0, 0, 0);
                }
            }
            __syncthreads();  // A reads + pre1 reads done
            if (tid == 0) set_flag(flag1c, s + 1);

            float part[4] = {0.f, 0.f, 0.f, 0.f};
#pragma unroll
            for (int a2 = 0; a2 < 2; ++a2) {
                int j = (w + 8 * a2) * 16 + col;
#pragma unroll
                for (int r = 0; r < 4; ++r) {
                    int m = quad * 4 + r;
                    float iv = sigf(acc[0 + a2][r]);
                    float fv = sigf(acc[2 + a2][r]);
                    float gv = tanhf2(acc[4 + a2][r]);
                    float ov = sigf(acc[6 + a2][r]);
                    float c = fv * cst[a2 * 4 + r] + iv * gv;
                    cst[a2 * 4 + r] = c;
                    float hv = ov * tanhf2(c);
                    Ash[m * LDA1 + j] = (_Float16)hv;
                    part[r] += fmaxf(hv, 0.f) * wf[a2];
                }
            }
#pragma unroll
            for (int off = 1; off < 16; off <<= 1)
#pragma unroll
                for (int r = 0; r < 4; ++r) part[r] += __shfl_xor(part[r], off, 16);
            if (col == 0) {
#pragma unroll
                for (int r = 0; r < 4; ++r) red[w][quad * 4 + r] = part[r];
            }
            __syncthreads();
            if (tid < 16) {
                float t = bfcv;
#pragma unroll
                for (int ww = 0; ww < 8; ++ww) t += red[ww][tid];
                out[(size_t)s * BATCH + c0b + tid] = t;
            }
        }
    }
}

// ---------------------------------------------------------------------------
extern "C" void kernel_launch(void* const* d_in, const int* in_sizes, int n_in,
                              void* d_out, int out_size, void* d_ws, size_t ws_size,
                              hipStream_t stream) {
    const float* x    = (const float*)d_in[0];
    const float* h0   = (const float*)d_in[1];
    const float* c0   = (const float*)d_in[2];
    const float* Wih0 = (const float*)d_in[3];
    const float* Whh0 = (const float*)d_in[4];
    const float* bih0 = (const float*)d_in[5];
    const float* bhh0 = (const float*)d_in[6];
    const float* Wih1 = (const float*)d_in[7];
    const float* Whh1 = (const float*)d_in[8];
    const float* bih1 = (const float*)d_in[9];
    const float* bhh1 = (const float*)d_in[10];
    const float* Wfc  = (const float*)d_in[11];
    const float* bfc  = (const float*)d_in[12];
    float* out = (float*)d_out;

    char* ws = (char*)d_ws;
    constexpr size_t OFF_WCAT0 = 0;
    constexpr size_t SZ_WCAT0 = (size_t)GATES * K0 * 2;       // 589824
    constexpr size_t OFF_WIH1 = OFF_WCAT0 + SZ_WCAT0;
    constexpr size_t SZ_W1 = (size_t)GATES * HID * 2;         // 524288
    constexpr size_t OFF_WHH1 = OFF_WIH1 + SZ_W1;
    constexpr size_t OFF_B0 = OFF_WHH1 + SZ_W1;
    constexpr size_t OFF_B1 = OFF_B0 + 4096;
    constexpr size_t OFF_FLAGS = OFF_B1 + 4096;
    constexpr size_t SZ_FLAGS = 16384;
    constexpr size_t OFF_RINGS = OFF_FLAGS + SZ_FLAGS;

    _Float16* wcat0 = (_Float16*)(ws + OFF_WCAT0);
    _Float16* wih1h = (_Float16*)(ws + OFF_WIH1);
    _Float16* whh1h = (_Float16*)(ws + OFF_WHH1);
    float* b0 = (float*)(ws + OFF_B0);
    float* b1 = (float*)(ws + OFF_B1);
    int* flags = (int*)(ws + OFF_FLAGS);

    // ring sizing from ws_size (deterministic across calls -> graph-safe)
    int R0 = 128, R1 = 64;  // hs0 slot = 32 KB; pre1 slot (all 4 groups) = 256 KB
    while (OFF_RINGS + (size_t)R0 * 32768 + (size_t)R1 * 262144 > ws_size &&
           (R0 > 8 || R1 > 8)) {
        if (R1 > 8) R1 >>= 1;
        else R0 >>= 1;
    }
    _Float16* hs0ring = (_Float16*)(ws + OFF_RINGS);
    float* pre1ring = (float*)(ws + OFF_RINGS + (size_t)R0 * 32768);

    hipMemsetAsync(flags, 0, SZ_FLAGS, stream);
    prep_weights<<<256, 256, 0, stream>>>(Wih0, Whh0, bih0, bhh0, Wih1, Whh1, bih1, bhh1,
                                          wcat0, wih1h, whh1h, b0, b1);
    lstm_scan<<<12, 512, 0, stream>>>(x, h0, c0, wcat0, wih1h, whh1h, b0, b1, Wfc, bfc,
                                      hs0ring, pre1ring, flags, out, R0, R1);
}